// Round 9
// baseline (412.761 us; speedup 1.0000x reference)
//
#include <hip/hip_runtime.h>
#include <stdint.h>

typedef __bf16 bf16_t;
typedef __attribute__((ext_vector_type(8))) __bf16 bf16x8;
typedef __attribute__((ext_vector_type(4))) __bf16 bf16x4;
typedef __attribute__((ext_vector_type(4))) float f32x4;

#define NB_ 32
#define NT_ 3136
#define DIN_ 192
#define DOUT_ 384
#define NH_ 6
#define HD_ 64
#define NW_ 49
#define WSZ_ 16
#define TP_ 784
#define MLP_ 1536

__device__ __forceinline__ f32x4 mfma16(bf16x8 a, bf16x8 b, f32x4 c) {
  return __builtin_amdgcn_mfma_f32_16x16x32_bf16(a, b, c, 0, 0, 0);
}

__device__ __forceinline__ void gload_lds16(const bf16_t* g, bf16_t* l) {
  __builtin_amdgcn_global_load_lds(
      (const __attribute__((address_space(1))) void*)((const void*)g),
      (__attribute__((address_space(3))) void*)l, 16, 0, 0);
}

// ---------------- one-shot f32 -> bf16 weight cache ----------------
// ranges (blocks of 2048 elems): qkv 108 | res 36 | proj 72 | fc1 288 | fc2 288
__global__ void cvt_kernel(const float* __restrict__ s0, const float* __restrict__ s1,
                           const float* __restrict__ s2, const float* __restrict__ s3,
                           const float* __restrict__ s4, bf16_t* __restrict__ d0,
                           bf16_t* __restrict__ d1, bf16_t* __restrict__ d2,
                           bf16_t* __restrict__ d3, bf16_t* __restrict__ d4) {
  const int b = blockIdx.x;
  const float* s; bf16_t* d; long off;
  if (b < 108)      { s = s0; d = d0; off = (long)b * 2048; }
  else if (b < 144) { s = s1; d = d1; off = (long)(b - 108) * 2048; }
  else if (b < 216) { s = s2; d = d2; off = (long)(b - 144) * 2048; }
  else if (b < 504) { s = s3; d = d3; off = (long)(b - 216) * 2048; }
  else              { s = s4; d = d4; off = (long)(b - 504) * 2048; }
  off += (long)threadIdx.x * 8;
  const float4 a = *(const float4*)(s + off);
  const float4 c = *(const float4*)(s + off + 4);
  bf16x8 o;
  o[0] = (bf16_t)a.x; o[1] = (bf16_t)a.y; o[2] = (bf16_t)a.z; o[3] = (bf16_t)a.w;
  o[4] = (bf16_t)c.x; o[5] = (bf16_t)c.y; o[6] = (bf16_t)c.z; o[7] = (bf16_t)c.w;
  *(bf16x8*)(d + off) = o;
}

// ---------------- LayerNorm f32 -> bf16 ----------------
template <int D>
__global__ void ln_f32_kernel(const float* __restrict__ in, const float* __restrict__ w,
                              const float* __restrict__ bvec, bf16_t* __restrict__ out) {
  const int row = blockIdx.x * 4 + (threadIdx.x >> 6);
  const int lane = threadIdx.x & 63;
  constexpr int PER = D / 64;
  const float* x = in + (long)row * D;
  float v[PER];
  float s = 0.f;
#pragma unroll
  for (int i = 0; i < PER; i++) { v[i] = x[lane * PER + i]; s += v[i]; }
#pragma unroll
  for (int off = 1; off < 64; off <<= 1) s += __shfl_xor(s, off);
  const float mu = s * (1.f / D);
  float s2 = 0.f;
#pragma unroll
  for (int i = 0; i < PER; i++) { const float d = v[i] - mu; s2 += d * d; }
#pragma unroll
  for (int off = 1; off < 64; off <<= 1) s2 += __shfl_xor(s2, off);
  const float rstd = rsqrtf(s2 * (1.f / D) + 1e-5f);
  bf16_t* o = out + (long)row * D;
#pragma unroll
  for (int i = 0; i < PER; i++) {
    const int c = lane * PER + i;
    o[c] = (bf16_t)((v[i] - mu) * rstd * w[c] + bvec[c]);
  }
}

// ---------------- LayerNorm bf16 -> bf16 ----------------
template <int D>
__global__ void ln_bf16_kernel(const bf16_t* __restrict__ in, const float* __restrict__ w,
                               const float* __restrict__ bvec, bf16_t* __restrict__ out) {
  const int row = blockIdx.x * 4 + (threadIdx.x >> 6);
  const int lane = threadIdx.x & 63;
  constexpr int PER = D / 64;
  const bf16_t* x = in + (long)row * D;
  float v[PER];
  float s = 0.f;
#pragma unroll
  for (int i = 0; i < PER; i++) { v[i] = (float)x[lane * PER + i]; s += v[i]; }
#pragma unroll
  for (int off = 1; off < 64; off <<= 1) s += __shfl_xor(s, off);
  const float mu = s * (1.f / D);
  float s2 = 0.f;
#pragma unroll
  for (int i = 0; i < PER; i++) { const float d = v[i] - mu; s2 += d * d; }
#pragma unroll
  for (int off = 1; off < 64; off <<= 1) s2 += __shfl_xor(s2, off);
  const float rstd = rsqrtf(s2 * (1.f / D) + 1e-5f);
  bf16_t* o = out + (long)row * D;
#pragma unroll
  for (int i = 0; i < PER; i++) {
    const int c = lane * PER + i;
    o[c] = (bf16_t)((v[i] - mu) * rstd * w[c] + bvec[c]);
  }
}

// ------ GEMM: C = act(A @ W^T + bias) (+res) (optional fused q-pool) ------
// BM x 128 tile, BK=64, 4 waves (2x2), mfma 16x16x32 bf16, all-bf16 operands.
// K-loop = m97 structure: global_load_lds(16B) staging, single LDS buffer,
// 2x __syncthreads per K-step. Bank-conflict-free reads via SOURCE pre-swizzle
// (gload_lds dest stays linear; global col XOR (srow&7)<<3; read col XOR
// (row&7)<<4 bytes — same involution both sides).
// Non-POOL: operand-SWAPPED mfma(wf, af): lane holds 4 consecutive N-cols of one
// M-row -> packed bf16x4/float4 stores + vector bias/residual loads.
// POOL: classic order; A rows gathered m=b*3136+j*4+q -> t=b*3136+q*784+j; epilogue
// maxes the lane's 4 acc rows -> row m/4 (q_stride pool), bias after max.
// Grid XCD-swizzled (m204 bijective) for A-panel L2 locality.
template <int ACT, int HASRES, int POOL, int OF32, int RF32, int BM>
__global__ __launch_bounds__(256) void gemm_t(
    const bf16_t* __restrict__ A, const bf16_t* __restrict__ W,
    const float* __restrict__ bias, const void* __restrict__ resv,
    void* __restrict__ Cv, int M, int N, int K) {
  constexpr int PA = BM / 32;
  __shared__ __align__(16) char LDSB[BM * 128 + 128 * 128];
  char* AsB = LDSB;
  char* WsB = LDSB + BM * 128;

  // m204 bijective XCD swizzle
  const int nwg = gridDim.x;
  const int q = nwg >> 3, rm = nwg & 7;
  const int xcd = blockIdx.x & 7, idx = blockIdx.x >> 3;
  const int wg = (xcd < rm ? xcd * (q + 1) : rm * (q + 1) + (xcd - rm) * q) + idx;

  const int nbn = N >> 7;
  const int bmi = wg / nbn;
  const int bni = wg - bmi * nbn;
  const int m0 = bmi * BM, n0 = bni << 7;
  const int tid = threadIdx.x;
  const int lane = tid & 63;
  const int wid = tid >> 6;
  const int wr = (wid >> 1) * (BM / 2), wc = (wid & 1) * 64;
  const int l15 = lane & 15;
  const int lkb = (lane >> 4) << 4;          // col-byte within 128B row
  const int srow = tid >> 3;                 // 0..31 (staging row within chunk)
  const int scolsw = ((tid & 7) << 3) ^ ((srow & 7) << 3);  // pre-swizzled src col
  const int swzr = (l15 & 7) << 4;           // read-side swizzle

  f32x4 acc[PA][4];
  const f32x4 zero = {0.f, 0.f, 0.f, 0.f};
#pragma unroll
  for (int i = 0; i < PA; i++)
#pragma unroll
    for (int j = 0; j < 4; j++) acc[i][j] = zero;

  long arow[PA];
#pragma unroll
  for (int p = 0; p < PA; p++) {
    const int m = m0 + srow + p * 32;
    if constexpr (POOL) {
      const int b = m / NT_;
      const int mm = m - b * NT_;
      arow[p] = (long)b * NT_ + (mm & 3) * TP_ + (mm >> 2);
    } else {
      arow[p] = m;
    }
  }
  long wrow[4];
#pragma unroll
  for (int p = 0; p < 4; p++) wrow[p] = (long)(n0 + srow + p * 32);

  for (int k0 = 0; k0 < K; k0 += 64) {
    __syncthreads();   // prior iteration's LDS reads complete
#pragma unroll
    for (int p = 0; p < PA; p++)
      gload_lds16(A + arow[p] * K + k0 + scolsw, (bf16_t*)(AsB + p * 4096 + tid * 16));
#pragma unroll
    for (int p = 0; p < 4; p++)
      gload_lds16(W + wrow[p] * K + k0 + scolsw, (bf16_t*)(WsB + p * 4096 + tid * 16));
    __syncthreads();   // staging complete (vmcnt+lgkm drained by barrier semantics)
#pragma unroll
    for (int kk = 0; kk < 2; kk++) {
      bf16x8 af[PA], wf[4];
#pragma unroll
      for (int i = 0; i < PA; i++)
        af[i] = *(const bf16x8*)(AsB + (wr + i * 16 + l15) * 128 + ((kk * 64 + lkb) ^ swzr));
#pragma unroll
      for (int j = 0; j < 4; j++)
        wf[j] = *(const bf16x8*)(WsB + (wc + j * 16 + l15) * 128 + ((kk * 64 + lkb) ^ swzr));
#pragma unroll
      for (int i = 0; i < PA; i++)
#pragma unroll
        for (int j = 0; j < 4; j++) {
          if constexpr (POOL) acc[i][j] = mfma16(af[i], wf[j], acc[i][j]);
          else                acc[i][j] = mfma16(wf[j], af[i], acc[i][j]);
        }
    }
  }

  const int rg = (lane >> 4) * 4;
  if constexpr (POOL) {
#pragma unroll
    for (int j = 0; j < 4; j++) {
      const int gn = n0 + wc + j * 16 + l15;
      const float bv = bias[gn];
#pragma unroll
      for (int i = 0; i < PA; i++) {
        const float v = fmaxf(fmaxf(acc[i][j][0], acc[i][j][1]),
                              fmaxf(acc[i][j][2], acc[i][j][3])) + bv;
        const long pm = (long)((m0 + wr + i * 16 + rg) >> 2);
        ((bf16_t*)Cv)[pm * N + gn] = (bf16_t)v;
      }
    }
  } else {
    // swapped layout: lane holds C[m = wr+i*16+l15][n = wc+j*16+rg+r], r=0..3
#pragma unroll
    for (int i = 0; i < PA; i++) {
      const long gm = m0 + wr + i * 16 + l15;
#pragma unroll
      for (int j = 0; j < 4; j++) {
        const int gn = n0 + wc + j * 16 + rg;
        const float4 bv = *(const float4*)(bias + gn);
        float v[4] = {acc[i][j][0] + bv.x, acc[i][j][1] + bv.y,
                      acc[i][j][2] + bv.z, acc[i][j][3] + bv.w};
        if constexpr (ACT == 1) {
#pragma unroll
          for (int r = 0; r < 4; r++) {
            const float t2 = 1.5957691216f * (v[r] + 0.044715f * v[r] * v[r] * v[r]);
            v[r] = v[r] * (1.f - 1.f / (1.f + __expf(t2)));   // tanh-form GELU
          }
        }
        if constexpr (HASRES) {
          if constexpr (RF32) {
            const float4 rv = *(const float4*)((const float*)resv + gm * N + gn);
            v[0] += rv.x; v[1] += rv.y; v[2] += rv.z; v[3] += rv.w;
          } else {
            const bf16x4 rv = *(const bf16x4*)((const bf16_t*)resv + gm * N + gn);
#pragma unroll
            for (int r = 0; r < 4; r++) v[r] += (float)rv[r];
          }
        }
        if constexpr (OF32) {
          float4 o = {v[0], v[1], v[2], v[3]};
          *(float4*)((float*)Cv + gm * N + gn) = o;
        } else {
          bf16x4 o;
#pragma unroll
          for (int r = 0; r < 4; r++) o[r] = (bf16_t)v[r];
          *(bf16x4*)((bf16_t*)Cv + gm * N + gn) = o;
        }
      }
    }
  }
}

// ---------------- mask-unit attention: 4 waves/block, one (b_rel,h,w) per wave -------
__global__ __launch_bounds__(256) void attn_kernel(const bf16_t* __restrict__ qkv,
                                                   float* __restrict__ attn_out,
                                                   bf16_t* __restrict__ obuf) {
  __shared__ __align__(16) bf16_t Vs[4][64 * 64];
  __shared__ __align__(16) bf16_t Ps[4][16 * 64];
  const int wid = threadIdx.x >> 6;
  const int lane = threadIdx.x & 63;
  const int flat = blockIdx.x * 4 + wid;     // = (b_rel*6 + h)*49 + w
  const int w = flat % NW_;
  const int h = (flat / NW_) % NH_;
  const int b = flat / (NW_ * NH_);
  const int l15 = lane & 15, lk8 = (lane >> 4) * 8;
  const bf16_t* qb = qkv + (long)b * NT_ * (3 * DOUT_);
  bf16_t* Vw = Vs[wid];
  bf16_t* Pw = Ps[wid];

#pragma unroll
  for (int p = 0; p < 8; p++) {
    const int inner = p * 8 + (lane >> 3);
    const int col = (lane & 7) * 8;
    const bf16x8 t =
        *(const bf16x8*)(qb + (long)(inner * NW_ + w) * (3 * DOUT_) + 2 * DOUT_ + h * HD_ + col);
    *(bf16x8*)&Vw[p * 512 + lane * 8] = t;
  }

  bf16x8 aq[2];
#pragma unroll
  for (int kc = 0; kc < 2; kc++) {
    const int d = kc * 32 + lk8;
    float qv[8];
#pragma unroll
    for (int e = 0; e < 8; e++) qv[e] = -1e30f;
#pragma unroll
    for (int qs = 0; qs < 4; qs++) {
      const bf16x8 t =
          *(const bf16x8*)(qb + (long)((qs * 16 + l15) * NW_ + w) * (3 * DOUT_) + h * HD_ + d);
#pragma unroll
      for (int e = 0; e < 8; e++) qv[e] = fmaxf(qv[e], (float)t[e]);
    }
    bf16x8 a;
#pragma unroll
    for (int e = 0; e < 8; e++) a[e] = (bf16_t)(qv[e] * 0.125f);
    aq[kc] = a;
  }

  f32x4 s4[4];
  const f32x4 zero = {0.f, 0.f, 0.f, 0.f};
#pragma unroll
  for (int nc = 0; nc < 4; nc++) s4[nc] = zero;
#pragma unroll
  for (int nc = 0; nc < 4; nc++) {
#pragma unroll
    for (int kc = 0; kc < 2; kc++) {
      const int tok = nc * 16 + l15;
      const int d = kc * 32 + lk8;
      const bf16x8 bk =
          *(const bf16x8*)(qb + (long)(tok * NW_ + w) * (3 * DOUT_) + DOUT_ + h * HD_ + d);
      s4[nc] = mfma16(aq[kc], bk, s4[nc]);
    }
  }

#pragma unroll
  for (int r = 0; r < 4; r++) {
    float mx = fmaxf(fmaxf(s4[0][r], s4[1][r]), fmaxf(s4[2][r], s4[3][r]));
#pragma unroll
    for (int off = 1; off < 16; off <<= 1) mx = fmaxf(mx, __shfl_xor(mx, off));
    float sm = 0.f;
#pragma unroll
    for (int nc = 0; nc < 4; nc++) {
      const float p = __expf(s4[nc][r] - mx);
      s4[nc][r] = p;
      sm += p;
    }
#pragma unroll
    for (int off = 1; off < 16; off <<= 1) sm += __shfl_xor(sm, off);
    const float inv = 1.f / sm;
#pragma unroll
    for (int nc = 0; nc < 4; nc++) s4[nc][r] *= inv;
  }

  const int rg = (lane >> 4) * 4;
  float* aout = attn_out + (long)flat * (WSZ_ * 64);
#pragma unroll
  for (int nc = 0; nc < 4; nc++) {
#pragma unroll
    for (int r = 0; r < 4; r++) {
      const int row = rg + r, col = nc * 16 + l15;
      aout[row * 64 + col] = s4[nc][r];
      Pw[row * 64 + col] = (bf16_t)s4[nc][r];
    }
  }

  bf16x8 ap[2];
#pragma unroll
  for (int kc = 0; kc < 2; kc++) ap[kc] = *(const bf16x8*)&Pw[l15 * 64 + kc * 32 + lk8];

  f32x4 o4[4];
#pragma unroll
  for (int nc = 0; nc < 4; nc++) o4[nc] = zero;
#pragma unroll
  for (int nc = 0; nc < 4; nc++) {
#pragma unroll
    for (int kc = 0; kc < 2; kc++) {
      bf16x8 bv;
#pragma unroll
      for (int e = 0; e < 8; e++) bv[e] = Vw[(kc * 32 + lk8 + e) * 64 + nc * 16 + l15];
      o4[nc] = mfma16(ap[kc], bv, o4[nc]);
    }
  }

  bf16_t* ob = obuf + (long)b * TP_ * DOUT_;
#pragma unroll
  for (int nc = 0; nc < 4; nc++) {
#pragma unroll
    for (int r = 0; r < 4; r++) {
      const int wsr = rg + r;
      const int tprime = wsr * NW_ + w;
      const int chan = h * HD_ + nc * 16 + l15;
      ob[(long)tprime * DOUT_ + chan] = (bf16_t)o4[nc][r];
    }
  }
}

extern "C" void kernel_launch(void* const* d_in, const int* in_sizes, int n_in,
                              void* d_out, int out_size, void* d_ws, size_t ws_size,
                              hipStream_t stream) {
  const float* emb   = (const float*)d_in[0];
  const float* n1w   = (const float*)d_in[1];
  const float* n1b   = (const float*)d_in[2];
  const float* wqkv  = (const float*)d_in[3];
  const float* bqkv  = (const float*)d_in[4];
  const float* wproj = (const float*)d_in[5];
  const float* bproj = (const float*)d_in[6];
  const float* wres  = (const float*)d_in[7];
  const float* bres  = (const float*)d_in[8];
  const float* n2w   = (const float*)d_in[9];
  const float* n2b   = (const float*)d_in[10];
  const float* wfc1  = (const float*)d_in[11];
  const float* bfc1  = (const float*)d_in[12];
  const float* wfc2  = (const float*)d_in[13];
  const float* bfc2  = (const float*)d_in[14];
  float* out = (float*)d_out;

  const int BT = NB_ * NT_;    // 100352
  const int BTP = NB_ * TP_;   // 25088
  const int BSL = 8;           // batches per qkv/attn slice (4 slices)
  const int MSL = BSL * NT_;   // 25088 rows per slice

  // ws layout (118.85 MB; <= proven-safe 134.87 MB):
  //   [0, 57.80M):        qkvb slices / later h1 head
  //   [57.80M, 77.07M):   obuf bf16 (attn PV out) / later h1 tail
  //   [77.07M, 96.34M):   resp bf16 / later h0 bf16
  //   [96.34M, 115.61M):  emb1 bf16
  //   [115.61M, 118.85M): bf16 weight cache (qkv|res|proj|fc1|fc2)
  char* wsb = (char*)d_ws;
  bf16_t* qkvb = (bf16_t*)(wsb);
  bf16_t* h1   = (bf16_t*)(wsb);
  bf16_t* obuf = (bf16_t*)(wsb + 57802752L);
  bf16_t* resp = (bf16_t*)(wsb + 77070336L);
  bf16_t* h0   = resp;
  bf16_t* emb1 = (bf16_t*)(wsb + 96337920L);
  bf16_t* wbqkv = (bf16_t*)(wsb + 115605504L);
  bf16_t* wbres = wbqkv + 221184L;
  bf16_t* wbproj = wbres + 73728L;
  bf16_t* wbfc1 = wbproj + 147456L;
  bf16_t* wbfc2 = wbfc1 + 589824L;
  // d_out overlays: x = LN1 output (bf16) in probs half; per-batch strides match
  // (1,204,224 B), attn slice s overwrites x[batches 8s..8s+7] AFTER qkv s used them.
  float*  prob = out + 9633792L;
  bf16_t* x    = (bf16_t*)(out + 9633792L);

  // 0. weight cache f32 -> bf16
  cvt_kernel<<<792, 256, 0, stream>>>(wqkv, wres, wproj, wfc1, wfc2,
                                      wbqkv, wbres, wbproj, wbfc1, wbfc2);
  // 1. LN1: emb f32 -> x bf16
  ln_f32_kernel<DIN_><<<BT / 4, 256, 0, stream>>>(emb, n1w, n1b, x);
  // 2. res projection + fused q-stride max-pool -> resp bf16
  gemm_t<0, 0, 1, 0, 0, 128><<<(BT / 128) * (DOUT_ / 128), 256, 0, stream>>>(
      x, wbres, bres, nullptr, resp, BT, DOUT_, DIN_);
  // 3. qkv + attention, 4 batch-slices of 8
  for (int s = 0; s < 4; s++) {
    gemm_t<0, 0, 0, 0, 0, 128><<<(MSL / 128) * (3 * DOUT_ / 128), 256, 0, stream>>>(
        x + (long)s * MSL * DIN_, wbqkv, bqkv, nullptr, qkvb, MSL, 3 * DOUT_, DIN_);
    attn_kernel<<<BSL * NH_ * NW_ / 4, 256, 0, stream>>>(
        qkvb, prob + (long)s * 2408448L, obuf + (long)s * 2408448L);
  }
  // 4. attn proj + pooled residual -> emb1 bf16
  gemm_t<0, 1, 0, 0, 0, 64><<<(BTP / 64) * (DOUT_ / 128), 256, 0, stream>>>(
      obuf, wbproj, bproj, resp, emb1, BTP, DOUT_, DOUT_);
  // 5. LN2: emb1 bf16 -> h0 bf16
  ln_bf16_kernel<DOUT_><<<BTP / 4, 256, 0, stream>>>(emb1, n2w, n2b, h0);
  // 6. fc1 + GELU -> h1 bf16
  gemm_t<1, 0, 0, 0, 0, 128><<<(BTP / 128) * (MLP_ / 128), 256, 0, stream>>>(
      h0, wbfc1, bfc1, nullptr, h1, BTP, MLP_, DOUT_);
  // 7. fc2 + emb1 residual -> d_out emb half (f32)
  gemm_t<0, 1, 0, 1, 0, 64><<<(BTP / 64) * (DOUT_ / 128), 256, 0, stream>>>(
      h1, wbfc2, bfc2, emb1, out, BTP, DOUT_, MLP_);
}

// Round 10
// 384.366 us; speedup vs baseline: 1.0739x; 1.0739x over previous
//
#include <hip/hip_runtime.h>
#include <stdint.h>

typedef __bf16 bf16_t;
typedef __attribute__((ext_vector_type(8))) __bf16 bf16x8;
typedef __attribute__((ext_vector_type(4))) __bf16 bf16x4;
typedef __attribute__((ext_vector_type(4))) float f32x4;

#define NB_ 32
#define NT_ 3136
#define DIN_ 192
#define DOUT_ 384
#define NH_ 6
#define HD_ 64
#define NW_ 49
#define WSZ_ 16
#define TP_ 784
#define MLP_ 1536

__device__ __forceinline__ f32x4 mfma16(bf16x8 a, bf16x8 b, f32x4 c) {
  return __builtin_amdgcn_mfma_f32_16x16x32_bf16(a, b, c, 0, 0, 0);
}

__device__ __forceinline__ void gload_lds16(const bf16_t* g, bf16_t* l) {
  __builtin_amdgcn_global_load_lds(
      (const __attribute__((address_space(1))) void*)((const void*)g),
      (__attribute__((address_space(3))) void*)l, 16, 0, 0);
}

// ---------------- one-shot f32 -> bf16 weight cache ----------------
// ranges (blocks of 2048 elems): qkv 108 | res 36 | proj 72 | fc1 288 | fc2 288
__global__ void cvt_kernel(const float* __restrict__ s0, const float* __restrict__ s1,
                           const float* __restrict__ s2, const float* __restrict__ s3,
                           const float* __restrict__ s4, bf16_t* __restrict__ d0,
                           bf16_t* __restrict__ d1, bf16_t* __restrict__ d2,
                           bf16_t* __restrict__ d3, bf16_t* __restrict__ d4) {
  const int b = blockIdx.x;
  const float* s; bf16_t* d; long off;
  if (b < 108)      { s = s0; d = d0; off = (long)b * 2048; }
  else if (b < 144) { s = s1; d = d1; off = (long)(b - 108) * 2048; }
  else if (b < 216) { s = s2; d = d2; off = (long)(b - 144) * 2048; }
  else if (b < 504) { s = s3; d = d3; off = (long)(b - 216) * 2048; }
  else              { s = s4; d = d4; off = (long)(b - 504) * 2048; }
  off += (long)threadIdx.x * 8;
  const float4 a = *(const float4*)(s + off);
  const float4 c = *(const float4*)(s + off + 4);
  bf16x8 o;
  o[0] = (bf16_t)a.x; o[1] = (bf16_t)a.y; o[2] = (bf16_t)a.z; o[3] = (bf16_t)a.w;
  o[4] = (bf16_t)c.x; o[5] = (bf16_t)c.y; o[6] = (bf16_t)c.z; o[7] = (bf16_t)c.w;
  *(bf16x8*)(d + off) = o;
}

// ---------------- LayerNorm f32 -> bf16 ----------------
template <int D>
__global__ void ln_f32_kernel(const float* __restrict__ in, const float* __restrict__ w,
                              const float* __restrict__ bvec, bf16_t* __restrict__ out) {
  const int row = blockIdx.x * 4 + (threadIdx.x >> 6);
  const int lane = threadIdx.x & 63;
  constexpr int PER = D / 64;
  const float* x = in + (long)row * D;
  float v[PER];
  float s = 0.f;
#pragma unroll
  for (int i = 0; i < PER; i++) { v[i] = x[lane * PER + i]; s += v[i]; }
#pragma unroll
  for (int off = 1; off < 64; off <<= 1) s += __shfl_xor(s, off);
  const float mu = s * (1.f / D);
  float s2 = 0.f;
#pragma unroll
  for (int i = 0; i < PER; i++) { const float d = v[i] - mu; s2 += d * d; }
#pragma unroll
  for (int off = 1; off < 64; off <<= 1) s2 += __shfl_xor(s2, off);
  const float rstd = rsqrtf(s2 * (1.f / D) + 1e-5f);
  bf16_t* o = out + (long)row * D;
#pragma unroll
  for (int i = 0; i < PER; i++) {
    const int c = lane * PER + i;
    o[c] = (bf16_t)((v[i] - mu) * rstd * w[c] + bvec[c]);
  }
}

// ---------------- LayerNorm bf16 -> bf16 ----------------
template <int D>
__global__ void ln_bf16_kernel(const bf16_t* __restrict__ in, const float* __restrict__ w,
                               const float* __restrict__ bvec, bf16_t* __restrict__ out) {
  const int row = blockIdx.x * 4 + (threadIdx.x >> 6);
  const int lane = threadIdx.x & 63;
  constexpr int PER = D / 64;
  const bf16_t* x = in + (long)row * D;
  float v[PER];
  float s = 0.f;
#pragma unroll
  for (int i = 0; i < PER; i++) { v[i] = (float)x[lane * PER + i]; s += v[i]; }
#pragma unroll
  for (int off = 1; off < 64; off <<= 1) s += __shfl_xor(s, off);
  const float mu = s * (1.f / D);
  float s2 = 0.f;
#pragma unroll
  for (int i = 0; i < PER; i++) { const float d = v[i] - mu; s2 += d * d; }
#pragma unroll
  for (int off = 1; off < 64; off <<= 1) s2 += __shfl_xor(s2, off);
  const float rstd = rsqrtf(s2 * (1.f / D) + 1e-5f);
  bf16_t* o = out + (long)row * D;
#pragma unroll
  for (int i = 0; i < PER; i++) {
    const int c = lane * PER + i;
    o[c] = (bf16_t)((v[i] - mu) * rstd * w[c] + bvec[c]);
  }
}

// ------ GEMM: C = act(A @ W^T + bias) (+res) (optional fused q-pool) ------
// BM x 128 tile, BK=64, 4 waves (2x2), mfma 16x16x32 bf16, all-bf16 operands.
// K-loop: DOUBLE-BUFFERED LDS, ONE __syncthreads per K-step. Loads for tile t+1
// are issued right after the barrier and drain at the NEXT barrier — a full
// compute phase hides their latency. gload_lds(16B) staging, source pre-swizzle
// (dest linear; global col XOR (srow&7)<<3 elems; read col XOR (row&7)<<4 B).
// Non-POOL: operand-SWAPPED mfma(wf, af): lane holds 4 consecutive N-cols of one
// M-row -> packed bf16x4/float4 stores + vector bias/residual loads.
// POOL: classic order; A rows gathered m=b*3136+j*4+q -> t=b*3136+q*784+j; epilogue
// maxes the lane's 4 acc rows -> row m/4 (q_stride pool), bias after max.
// Grid XCD-swizzled (m204 bijective) for A-panel L2 locality.
template <int ACT, int HASRES, int POOL, int OF32, int RF32, int BM>
__global__ __launch_bounds__(256) void gemm_t(
    const bf16_t* __restrict__ A, const bf16_t* __restrict__ W,
    const float* __restrict__ bias, const void* __restrict__ resv,
    void* __restrict__ Cv, int M, int N, int K) {
  constexpr int PA = BM / 32;
  constexpr int ABYTES = BM * 128;
  constexpr int BUFSZ = ABYTES + 128 * 128;
  __shared__ __align__(16) char LDSB[2 * BUFSZ];

  // m204 bijective XCD swizzle
  const int nwg = gridDim.x;
  const int q = nwg >> 3, rm = nwg & 7;
  const int xcd = blockIdx.x & 7, idx = blockIdx.x >> 3;
  const int wg = (xcd < rm ? xcd * (q + 1) : rm * (q + 1) + (xcd - rm) * q) + idx;

  const int nbn = N >> 7;
  const int bmi = wg / nbn;
  const int bni = wg - bmi * nbn;
  const int m0 = bmi * BM, n0 = bni << 7;
  const int tid = threadIdx.x;
  const int lane = tid & 63;
  const int wid = tid >> 6;
  const int wr = (wid >> 1) * (BM / 2), wc = (wid & 1) * 64;
  const int l15 = lane & 15;
  const int lkb = (lane >> 4) << 4;          // col-byte within 128B row
  const int srow = tid >> 3;                 // 0..31 (staging row within chunk)
  const int scolsw = ((tid & 7) << 3) ^ ((srow & 7) << 3);  // pre-swizzled src col
  const int swzr = (l15 & 7) << 4;           // read-side swizzle

  f32x4 acc[PA][4];
  const f32x4 zero = {0.f, 0.f, 0.f, 0.f};
#pragma unroll
  for (int i = 0; i < PA; i++)
#pragma unroll
    for (int j = 0; j < 4; j++) acc[i][j] = zero;

  long arow[PA];
#pragma unroll
  for (int p = 0; p < PA; p++) {
    const int m = m0 + srow + p * 32;
    if constexpr (POOL) {
      const int b = m / NT_;
      const int mm = m - b * NT_;
      arow[p] = (long)b * NT_ + (mm & 3) * TP_ + (mm >> 2);
    } else {
      arow[p] = m;
    }
  }
  long wrow[4];
#pragma unroll
  for (int p = 0; p < 4; p++) wrow[p] = (long)(n0 + srow + p * 32);

  auto stage = [&](int buf, int k0) {
    char* base = LDSB + buf * BUFSZ;
#pragma unroll
    for (int p = 0; p < PA; p++)
      gload_lds16(A + arow[p] * K + k0 + scolsw, (bf16_t*)(base + p * 4096 + tid * 16));
#pragma unroll
    for (int p = 0; p < 4; p++)
      gload_lds16(W + wrow[p] * K + k0 + scolsw,
                  (bf16_t*)(base + ABYTES + p * 4096 + tid * 16));
  };

  const int nt = K >> 6;
  stage(0, 0);
  int cur = 0;
  for (int t = 0; t < nt; t++) {
    __syncthreads();   // drains stage(t) vmcnt + prior ds_reads (lgkm)
    if (t + 1 < nt) stage(cur ^ 1, (t + 1) << 6);   // in flight across compute(t)
    const char* base = LDSB + cur * BUFSZ;
#pragma unroll
    for (int kk = 0; kk < 2; kk++) {
      bf16x8 af[PA], wf[4];
#pragma unroll
      for (int i = 0; i < PA; i++)
        af[i] = *(const bf16x8*)(base + (wr + i * 16 + l15) * 128 + ((kk * 64 + lkb) ^ swzr));
#pragma unroll
      for (int j = 0; j < 4; j++)
        wf[j] = *(const bf16x8*)(base + ABYTES + (wc + j * 16 + l15) * 128 +
                                 ((kk * 64 + lkb) ^ swzr));
#pragma unroll
      for (int i = 0; i < PA; i++)
#pragma unroll
        for (int j = 0; j < 4; j++) {
          if constexpr (POOL) acc[i][j] = mfma16(af[i], wf[j], acc[i][j]);
          else                acc[i][j] = mfma16(wf[j], af[i], acc[i][j]);
        }
    }
    cur ^= 1;
  }

  const int rg = (lane >> 4) * 4;
  if constexpr (POOL) {
#pragma unroll
    for (int j = 0; j < 4; j++) {
      const int gn = n0 + wc + j * 16 + l15;
      const float bv = bias[gn];
#pragma unroll
      for (int i = 0; i < PA; i++) {
        const float v = fmaxf(fmaxf(acc[i][j][0], acc[i][j][1]),
                              fmaxf(acc[i][j][2], acc[i][j][3])) + bv;
        const long pm = (long)((m0 + wr + i * 16 + rg) >> 2);
        ((bf16_t*)Cv)[pm * N + gn] = (bf16_t)v;
      }
    }
  } else {
    // swapped layout: lane holds C[m = wr+i*16+l15][n = wc+j*16+rg+r], r=0..3
#pragma unroll
    for (int i = 0; i < PA; i++) {
      const long gm = m0 + wr + i * 16 + l15;
#pragma unroll
      for (int j = 0; j < 4; j++) {
        const int gn = n0 + wc + j * 16 + rg;
        const float4 bv = *(const float4*)(bias + gn);
        float v[4] = {acc[i][j][0] + bv.x, acc[i][j][1] + bv.y,
                      acc[i][j][2] + bv.z, acc[i][j][3] + bv.w};
        if constexpr (ACT == 1) {
#pragma unroll
          for (int r = 0; r < 4; r++) {
            const float t2 = 1.5957691216f * (v[r] + 0.044715f * v[r] * v[r] * v[r]);
            v[r] = v[r] * (1.f - 1.f / (1.f + __expf(t2)));   // tanh-form GELU
          }
        }
        if constexpr (HASRES) {
          if constexpr (RF32) {
            const float4 rv = *(const float4*)((const float*)resv + gm * N + gn);
            v[0] += rv.x; v[1] += rv.y; v[2] += rv.z; v[3] += rv.w;
          } else {
            const bf16x4 rv = *(const bf16x4*)((const bf16_t*)resv + gm * N + gn);
#pragma unroll
            for (int r = 0; r < 4; r++) v[r] += (float)rv[r];
          }
        }
        if constexpr (OF32) {
          float4 o = {v[0], v[1], v[2], v[3]};
          *(float4*)((float*)Cv + gm * N + gn) = o;
        } else {
          bf16x4 o;
#pragma unroll
          for (int r = 0; r < 4; r++) o[r] = (bf16_t)v[r];
          *(bf16x4*)((bf16_t*)Cv + gm * N + gn) = o;
        }
      }
    }
  }
}

// ---------------- mask-unit attention: 4 waves/block, one (b_rel,h,w) per wave -------
__global__ __launch_bounds__(256) void attn_kernel(const bf16_t* __restrict__ qkv,
                                                   float* __restrict__ attn_out,
                                                   bf16_t* __restrict__ obuf) {
  __shared__ __align__(16) bf16_t Vs[4][64 * 64];
  __shared__ __align__(16) bf16_t Ps[4][16 * 64];
  const int wid = threadIdx.x >> 6;
  const int lane = threadIdx.x & 63;
  const int flat = blockIdx.x * 4 + wid;     // = (b_rel*6 + h)*49 + w
  const int w = flat % NW_;
  const int h = (flat / NW_) % NH_;
  const int b = flat / (NW_ * NH_);
  const int l15 = lane & 15, lk8 = (lane >> 4) * 8;
  const bf16_t* qb = qkv + (long)b * NT_ * (3 * DOUT_);
  bf16_t* Vw = Vs[wid];
  bf16_t* Pw = Ps[wid];

#pragma unroll
  for (int p = 0; p < 8; p++) {
    const int inner = p * 8 + (lane >> 3);
    const int col = (lane & 7) * 8;
    const bf16x8 t =
        *(const bf16x8*)(qb + (long)(inner * NW_ + w) * (3 * DOUT_) + 2 * DOUT_ + h * HD_ + col);
    *(bf16x8*)&Vw[p * 512 + lane * 8] = t;
  }

  bf16x8 aq[2];
#pragma unroll
  for (int kc = 0; kc < 2; kc++) {
    const int d = kc * 32 + lk8;
    float qv[8];
#pragma unroll
    for (int e = 0; e < 8; e++) qv[e] = -1e30f;
#pragma unroll
    for (int qs = 0; qs < 4; qs++) {
      const bf16x8 t =
          *(const bf16x8*)(qb + (long)((qs * 16 + l15) * NW_ + w) * (3 * DOUT_) + h * HD_ + d);
#pragma unroll
      for (int e = 0; e < 8; e++) qv[e] = fmaxf(qv[e], (float)t[e]);
    }
    bf16x8 a;
#pragma unroll
    for (int e = 0; e < 8; e++) a[e] = (bf16_t)(qv[e] * 0.125f);
    aq[kc] = a;
  }

  f32x4 s4[4];
  const f32x4 zero = {0.f, 0.f, 0.f, 0.f};
#pragma unroll
  for (int nc = 0; nc < 4; nc++) s4[nc] = zero;
#pragma unroll
  for (int nc = 0; nc < 4; nc++) {
#pragma unroll
    for (int kc = 0; kc < 2; kc++) {
      const int tok = nc * 16 + l15;
      const int d = kc * 32 + lk8;
      const bf16x8 bk =
          *(const bf16x8*)(qb + (long)(tok * NW_ + w) * (3 * DOUT_) + DOUT_ + h * HD_ + d);
      s4[nc] = mfma16(aq[kc], bk, s4[nc]);
    }
  }

#pragma unroll
  for (int r = 0; r < 4; r++) {
    float mx = fmaxf(fmaxf(s4[0][r], s4[1][r]), fmaxf(s4[2][r], s4[3][r]));
#pragma unroll
    for (int off = 1; off < 16; off <<= 1) mx = fmaxf(mx, __shfl_xor(mx, off));
    float sm = 0.f;
#pragma unroll
    for (int nc = 0; nc < 4; nc++) {
      const float p = __expf(s4[nc][r] - mx);
      s4[nc][r] = p;
      sm += p;
    }
#pragma unroll
    for (int off = 1; off < 16; off <<= 1) sm += __shfl_xor(sm, off);
    const float inv = 1.f / sm;
#pragma unroll
    for (int nc = 0; nc < 4; nc++) s4[nc][r] *= inv;
  }

  const int rg = (lane >> 4) * 4;
  float* aout = attn_out + (long)flat * (WSZ_ * 64);
#pragma unroll
  for (int nc = 0; nc < 4; nc++) {
#pragma unroll
    for (int r = 0; r < 4; r++) {
      const int row = rg + r, col = nc * 16 + l15;
      aout[row * 64 + col] = s4[nc][r];
      Pw[row * 64 + col] = (bf16_t)s4[nc][r];
    }
  }

  bf16x8 ap[2];
#pragma unroll
  for (int kc = 0; kc < 2; kc++) ap[kc] = *(const bf16x8*)&Pw[l15 * 64 + kc * 32 + lk8];

  f32x4 o4[4];
#pragma unroll
  for (int nc = 0; nc < 4; nc++) o4[nc] = zero;
#pragma unroll
  for (int nc = 0; nc < 4; nc++) {
#pragma unroll
    for (int kc = 0; kc < 2; kc++) {
      bf16x8 bv;
#pragma unroll
      for (int e = 0; e < 8; e++) bv[e] = Vw[(kc * 32 + lk8 + e) * 64 + nc * 16 + l15];
      o4[nc] = mfma16(ap[kc], bv, o4[nc]);
    }
  }

  bf16_t* ob = obuf + (long)b * TP_ * DOUT_;
#pragma unroll
  for (int nc = 0; nc < 4; nc++) {
#pragma unroll
    for (int r = 0; r < 4; r++) {
      const int wsr = rg + r;
      const int tprime = wsr * NW_ + w;
      const int chan = h * HD_ + nc * 16 + l15;
      ob[(long)tprime * DOUT_ + chan] = (bf16_t)o4[nc][r];
    }
  }
}

extern "C" void kernel_launch(void* const* d_in, const int* in_sizes, int n_in,
                              void* d_out, int out_size, void* d_ws, size_t ws_size,
                              hipStream_t stream) {
  const float* emb   = (const float*)d_in[0];
  const float* n1w   = (const float*)d_in[1];
  const float* n1b   = (const float*)d_in[2];
  const float* wqkv  = (const float*)d_in[3];
  const float* bqkv  = (const float*)d_in[4];
  const float* wproj = (const float*)d_in[5];
  const float* bproj = (const float*)d_in[6];
  const float* wres  = (const float*)d_in[7];
  const float* bres  = (const float*)d_in[8];
  const float* n2w   = (const float*)d_in[9];
  const float* n2b   = (const float*)d_in[10];
  const float* wfc1  = (const float*)d_in[11];
  const float* bfc1  = (const float*)d_in[12];
  const float* wfc2  = (const float*)d_in[13];
  const float* bfc2  = (const float*)d_in[14];
  float* out = (float*)d_out;

  const int BT = NB_ * NT_;    // 100352
  const int BTP = NB_ * TP_;   // 25088
  const int BSL = 8;           // batches per qkv/attn slice (4 slices)
  const int MSL = BSL * NT_;   // 25088 rows per slice

  // ws layout (118.85 MB; <= proven-safe 134.87 MB):
  //   [0, 57.80M):        qkvb slices / later h1 head
  //   [57.80M, 77.07M):   obuf bf16 (attn PV out) / later h1 tail
  //   [77.07M, 96.34M):   resp bf16 / later h0 bf16
  //   [96.34M, 115.61M):  emb1 bf16
  //   [115.61M, 118.85M): bf16 weight cache (qkv|res|proj|fc1|fc2)
  char* wsb = (char*)d_ws;
  bf16_t* qkvb = (bf16_t*)(wsb);
  bf16_t* h1   = (bf16_t*)(wsb);
  bf16_t* obuf = (bf16_t*)(wsb + 57802752L);
  bf16_t* resp = (bf16_t*)(wsb + 77070336L);
  bf16_t* h0   = resp;
  bf16_t* emb1 = (bf16_t*)(wsb + 96337920L);
  bf16_t* wbqkv = (bf16_t*)(wsb + 115605504L);
  bf16_t* wbres = wbqkv + 221184L;
  bf16_t* wbproj = wbres + 73728L;
  bf16_t* wbfc1 = wbproj + 147456L;
  bf16_t* wbfc2 = wbfc1 + 589824L;
  // d_out overlays: x = LN1 output (bf16) in probs half; per-batch strides match
  // (1,204,224 B), attn slice s overwrites x[batches 8s..8s+7] AFTER qkv s used them.
  float*  prob = out + 9633792L;
  bf16_t* x    = (bf16_t*)(out + 9633792L);

  // 0. weight cache f32 -> bf16
  cvt_kernel<<<792, 256, 0, stream>>>(wqkv, wres, wproj, wfc1, wfc2,
                                      wbqkv, wbres, wbproj, wbfc1, wbfc2);
  // 1. LN1: emb f32 -> x bf16
  ln_f32_kernel<DIN_><<<BT / 4, 256, 0, stream>>>(emb, n1w, n1b, x);
  // 2. res projection + fused q-stride max-pool -> resp bf16
  gemm_t<0, 0, 1, 0, 0, 128><<<(BT / 128) * (DOUT_ / 128), 256, 0, stream>>>(
      x, wbres, bres, nullptr, resp, BT, DOUT_, DIN_);
  // 3. qkv + attention, 4 batch-slices of 8
  for (int s = 0; s < 4; s++) {
    gemm_t<0, 0, 0, 0, 0, 128><<<(MSL / 128) * (3 * DOUT_ / 128), 256, 0, stream>>>(
        x + (long)s * MSL * DIN_, wbqkv, bqkv, nullptr, qkvb, MSL, 3 * DOUT_, DIN_);
    attn_kernel<<<BSL * NH_ * NW_ / 4, 256, 0, stream>>>(
        qkvb, prob + (long)s * 2408448L, obuf + (long)s * 2408448L);
  }
  // 4. attn proj + pooled residual -> emb1 bf16
  gemm_t<0, 1, 0, 0, 0, 64><<<(BTP / 64) * (DOUT_ / 128), 256, 0, stream>>>(
      obuf, wbproj, bproj, resp, emb1, BTP, DOUT_, DOUT_);
  // 5. LN2: emb1 bf16 -> h0 bf16
  ln_bf16_kernel<DOUT_><<<BTP / 4, 256, 0, stream>>>(emb1, n2w, n2b, h0);
  // 6. fc1 + GELU -> h1 bf16
  gemm_t<1, 0, 0, 0, 0, 128><<<(BTP / 128) * (MLP_ / 128), 256, 0, stream>>>(
      h0, wbfc1, bfc1, nullptr, h1, BTP, MLP_, DOUT_);
  // 7. fc2 + emb1 residual -> d_out emb half (f32)
  gemm_t<0, 1, 0, 1, 0, 64><<<(BTP / 64) * (DOUT_ / 128), 256, 0, stream>>>(
      h1, wbfc2, bfc2, emb1, out, BTP, DOUT_, MLP_);
}